// Round 12
// baseline (401.902 us; speedup 1.0000x reference)
//
#include <hip/hip_runtime.h>

#define HW 65536  // 256*256

typedef __bf16 bf16x8 __attribute__((ext_vector_type(8)));
typedef float f32x4 __attribute__((ext_vector_type(4)));

__device__ __forceinline__ float b2f(unsigned short u) {
    return __uint_as_float(((unsigned)u) << 16);
}
__device__ __forceinline__ unsigned short f2bu(float f) {
    unsigned u = __float_as_uint(f);
    return (unsigned short)((u + 0x7FFFu + ((u >> 16) & 1u)) >> 16);
}
// unpack a u32 holding 2 bf16 -> 2 floats (1 VALU op each)
__device__ __forceinline__ void up2(unsigned u, float& lo, float& hi) {
    lo = __uint_as_float(u << 16);
    hi = __uint_as_float(u & 0xFFFF0000u);
}

// ---------------------------------------------------------------------------
// K0: fold 6 depthwise kernels -> combined 21-tap h + 21-tap v per tensor.
__global__ void k_prep(const float* k11, const float* k12, const float* k13,
                       const float* k14, const float* k15, const float* k16,
                       const float* k21, const float* k22, const float* k23,
                       const float* k24, const float* k25, const float* k26,
                       const float* bdw, float* wcomb, float* bias) {
    int c = threadIdx.x;
    if (c >= 64) return;
    float* wh1 = wcomb;
    float* wv1 = wcomb + 1344;
    float* wh2 = wcomb + 2688;
    float* wv2 = wcomb + 4032;
    for (int j = 0; j < 21; j++) {
        wh1[c*21+j] = k13[c*21+j];
        wv1[c*21+j] = k16[c*21+j];
        wh2[c*21+j] = k23[c*21+j];
        wv2[c*21+j] = k26[c*21+j];
    }
    for (int j = 0; j < 11; j++) {
        wh1[c*21+j+5] += k12[c*11+j];
        wv1[c*21+j+5] += k15[c*11+j];
        wh2[c*21+j+5] += k22[c*11+j];
        wv2[c*21+j+5] += k25[c*11+j];
    }
    for (int j = 0; j < 7; j++) {
        wh1[c*21+j+7] += k11[c*7+j];
        wv1[c*21+j+7] += k14[c*7+j];
        wh2[c*21+j+7] += k21[c*7+j];
        wv2[c*21+j+7] += k24[c*7+j];
    }
    float s1 = 0.f, s2 = 0.f;
    for (int i = 0; i < 6; i++) { s1 += bdw[i*64+c]; s2 += bdw[(6+i)*64+c]; }
    bias[c] = s1; bias[64+c] = s2;
}

// ---------------------------------------------------------------------------
// K1 v3: LayerNorm, 1 px/thread, two-pass (var = E[x^2]-mu^2), with explicit
// compiler memory barriers between passes so the compiler CANNOT fuse them
// and keep 128 loads live (R11 failure: fused passes -> 256 VGPR -> 1.5%
// occupancy). Live state per thread ~ {s,q,mu,rs} -> ~32-40 VGPR; pass-2
// re-reads hit L1/L2. Grid 2048 x 128 = 16 waves/CU of TLP.
__global__ __launch_bounds__(128) void k_ln(
        const float* __restrict__ x1, const float* __restrict__ x2,
        const float* __restrict__ w1, const float* __restrict__ b1,
        const float* __restrict__ w2, const float* __restrict__ b2,
        unsigned short* __restrict__ o1, unsigned short* __restrict__ o2,
        unsigned short* __restrict__ s12) {
    __shared__ float cw1[64], cb1[64], cw2[64], cb2[64];
    int tid = threadIdx.x;
    if (tid < 64) {
        cw1[tid] = w1[tid]; cb1[tid] = b1[tid];
        cw2[tid] = w2[tid]; cb2[tid] = b2[tid];
    }
    __syncthreads();
    int p = blockIdx.x * 128 + tid;         // 0..262143
    int b = p >> 16, hw = p & (HW - 1);
    size_t base = (size_t)b * 64 * HW + hw;
    const float k1_64 = 0.015625f;
    // ---- x1: pass 1 (stats only) ----
    float s = 0.f, q = 0.f;
    #pragma unroll
    for (int c = 0; c < 64; c++) {
        float v = x1[base + (size_t)c * HW];
        s += v; q += v * v;
    }
    float mu = s * k1_64;
    float rs = rsqrtf(q * k1_64 - mu * mu + 1e-5f);
    asm volatile("" ::: "memory");   // forbid pass fusion / load caching
    // ---- x1: pass 2 (normalize + store o1) ----
    #pragma unroll
    for (int c = 0; c < 64; c++) {
        float v = x1[base + (size_t)c * HW];
        o1[base + (size_t)c * HW] = f2bu((v - mu) * rs * cw1[c] + cb1[c]);
    }
    asm volatile("" ::: "memory");
    // ---- x2: pass 1 ----
    s = 0.f; q = 0.f;
    #pragma unroll
    for (int c = 0; c < 64; c++) {
        float v = x2[base + (size_t)c * HW];
        s += v; q += v * v;
    }
    mu = s * k1_64;
    rs = rsqrtf(q * k1_64 - mu * mu + 1e-5f);
    asm volatile("" ::: "memory");
    // ---- x2: pass 2 (store o2; s12 = o1 + x2n, o1 read back via L2) ----
    #pragma unroll
    for (int c = 0; c < 64; c++) {
        float v = x2[base + (size_t)c * HW];
        float n2 = (v - mu) * rs * cw2[c] + cb2[c];
        o2[base + (size_t)c * HW] = f2bu(n2);
        s12[base + (size_t)c * HW] = f2bu(b2f(o1[base + (size_t)c * HW]) + n2);
    }
}

// ---------------------------------------------------------------------------
// K2: combined depthwise conv via MFMA Toeplitz (unchanged).
__global__ __launch_bounds__(256) void k_dw(
        const unsigned short* __restrict__ in1, const unsigned short* __restrict__ in2,
        const float* __restrict__ wcomb, const float* __restrict__ bias,
        unsigned short* __restrict__ o1, unsigned short* __restrict__ o2) {
    __shared__ __align__(16) unsigned short tileRaw[52 * 320];
    __shared__ __align__(16) unsigned short ThT[16][64];
    __shared__ __align__(16) unsigned short TvA[16][64];
    int which = blockIdx.y;
    const unsigned short* in = which ? in2 : in1;
    unsigned short* o = which ? o2 : o1;
    int bx = blockIdx.x;
    int bc = bx >> 3, tileid = bx & 7;
    int c = bc & 63;
    int h0 = tileid * 32;
    int tid = threadIdx.x;

    {
        const float* whp = wcomb + which * 2688 + c * 21;
        const float* wvp = whp + 1344;
        for (int i = tid; i < 2048; i += 256) {
            int mat = i >> 10;
            int idx = i & 1023;
            int n = idx >> 6, k = idx & 63;
            int j = k - n - 6;
            float v = (j >= 0 && j < 21) ? (mat ? wvp[j] : whp[j]) : 0.f;
            (mat ? &TvA[0][0] : &ThT[0][0])[idx] = f2bu(v);
        }
    }
    const unsigned short* src = in + (size_t)bc * HW;
    for (int idx = tid; idx < 52 * 40; idx += 256) {
        int row = idx / 40, u = idx - row * 40;
        int grow = h0 - 10 + row;
        uint4 val = make_uint4(0u, 0u, 0u, 0u);
        if ((unsigned)grow < 256u && u >= 2 && u < 34)
            val = *(const uint4*)(src + grow * 256 + (u - 2) * 8);
        *(uint4*)&tileRaw[row * 320 + ((u ^ ((row >> 1) & 7)) << 3)] = val;
    }
    float bs = bias[which * 64 + c];
    __syncthreads();

    int lane = tid & 63, wid = tid >> 6;
    int rA = lane & 15, g = lane >> 4, kf = g * 8;

    bf16x8 thB0 = *(const bf16x8*)&ThT[rA][kf];
    bf16x8 thB1 = *(const bf16x8*)&ThT[rA][32 + kf];
    bf16x8 tvA0 = *(const bf16x8*)&TvA[rA][kf];
    bf16x8 tvA1 = *(const bf16x8*)&TvA[rA][32 + kf];

    int ht = wid & 1, wgrp = wid >> 1;
    for (int t = 0; t < 8; t++) {
        int w0 = (wgrp * 8 + t) * 16;
        int ub = w0 >> 3;
        int hrow = ht * 16 + rA + 10;
        int xh = (hrow >> 1) & 7;
        bf16x8 ax0 = *(const bf16x8*)&tileRaw[hrow * 320 + (((ub + g) ^ xh) << 3)];
        bf16x8 ax1 = *(const bf16x8*)&tileRaw[hrow * 320 + (((ub + 4 + g) ^ xh) << 3)];
        int uvb = ub + 2 + (rA >> 3);
        int el = rA & 7;
        uint4 bv0, bv1;
        unsigned* pv0 = (unsigned*)&bv0;
        unsigned* pv1 = (unsigned*)&bv1;
        #pragma unroll
        for (int e2 = 0; e2 < 4; e2++) {
            int k0i = kf + 2 * e2;
            int r0 = ht * 16 + k0i - 6;  r0 = r0 < 0 ? 0 : (r0 > 51 ? 51 : r0);
            int r1 = ht * 16 + k0i - 5;  r1 = r1 < 0 ? 0 : (r1 > 51 ? 51 : r1);
            unsigned lo = tileRaw[r0 * 320 + ((uvb ^ ((r0 >> 1) & 7)) << 3) + el];
            unsigned hi = tileRaw[r1 * 320 + ((uvb ^ ((r1 >> 1) & 7)) << 3) + el];
            pv0[e2] = lo | (hi << 16);
            int k1i = 32 + kf + 2 * e2;
            int r2 = ht * 16 + k1i - 6;  r2 = r2 < 0 ? 0 : (r2 > 51 ? 51 : r2);
            int r3 = ht * 16 + k1i - 5;  r3 = r3 < 0 ? 0 : (r3 > 51 ? 51 : r3);
            unsigned lo2 = tileRaw[r2 * 320 + ((uvb ^ ((r2 >> 1) & 7)) << 3) + el];
            unsigned hi2 = tileRaw[r3 * 320 + ((uvb ^ ((r3 >> 1) & 7)) << 3) + el];
            pv1[e2] = lo2 | (hi2 << 16);
        }
        f32x4 acc = {bs, bs, bs, bs};
        acc = __builtin_amdgcn_mfma_f32_16x16x32_bf16(ax0, thB0, acc, 0, 0, 0);
        acc = __builtin_amdgcn_mfma_f32_16x16x32_bf16(ax1, thB1, acc, 0, 0, 0);
        acc = __builtin_amdgcn_mfma_f32_16x16x32_bf16(tvA0, *(bf16x8*)&bv0, acc, 0, 0, 0);
        acc = __builtin_amdgcn_mfma_f32_16x16x32_bf16(tvA1, *(bf16x8*)&bv1, acc, 0, 0, 0);
        int wc = w0 + rA;
        size_t obase = (size_t)bc * HW + wc;
        #pragma unroll
        for (int r = 0; r < 4; r++) {
            int hh = h0 + ht * 16 + 4 * g + r;
            o[obase + (size_t)hh * 256] = f2bu(acc[r]);
        }
    }
}

// ---------------------------------------------------------------------------
// K3: 1x1 conv (64x64), MFMA, kv-tiled V layout (unchanged).
__global__ __launch_bounds__(256) void k_pw(
        const unsigned short* __restrict__ in1, const unsigned short* __restrict__ in2,
        const float* __restrict__ wpw, const float* __restrict__ bpw,
        unsigned short* __restrict__ Eq, unsigned short* __restrict__ Fk,
        unsigned short* __restrict__ Fv) {
    __shared__ __align__(16) unsigned short Ws[64][72];
    __shared__ __align__(16) unsigned short Xs[64][260];
    __shared__ float sb[64];
    int tid = threadIdx.x;
    for (int i = tid; i < 4096; i += 256) Ws[i >> 6][i & 63] = f2bu(wpw[i]);
    if (tid < 64) sb[tid] = bpw[tid];
    int which = blockIdx.y;
    const unsigned short* in = which ? in2 : in1;
    int bx = blockIdx.x;
    int b = bx & 3;
    int h = ((bx >> 2) & 31) * 8 + (bx >> 7);
    const unsigned short* src = in + (size_t)b * 64 * HW + h * 256;
    for (int i = tid; i < 2048; i += 256) {
        int c = i >> 5, ch = i & 31;
        uint4 u = *(const uint4*)(src + (size_t)c * HW + ch * 8);
        *(uint2*)&Xs[c][ch * 8]     = make_uint2(u.x, u.y);
        *(uint2*)&Xs[c][ch * 8 + 4] = make_uint2(u.z, u.w);
    }
    __syncthreads();

    int lane = tid & 63, wv = tid >> 6;
    int rA = lane & 15, g = lane >> 4;
    int p_off = wv * 64;

    f32x4 acc[4][4];
    #pragma unroll
    for (int m = 0; m < 4; m++)
        #pragma unroll
        for (int n = 0; n < 4; n++) acc[m][n] = (f32x4){0.f, 0.f, 0.f, 0.f};

    #pragma unroll
    for (int ks = 0; ks < 2; ks++) {
        int c0 = ks * 32;
        bf16x8 a[4], bb[4];
        #pragma unroll
        for (int m = 0; m < 4; m++)
            a[m] = *(const bf16x8*)&Ws[16 * m + rA][c0 + 8 * g];
        #pragma unroll
        for (int n = 0; n < 4; n++) {
            int p = p_off + 16 * n + rA;
            uint4 bu;
            bu.x = (unsigned)Xs[c0 + 8*g + 0][p] | ((unsigned)Xs[c0 + 8*g + 1][p] << 16);
            bu.y = (unsigned)Xs[c0 + 8*g + 2][p] | ((unsigned)Xs[c0 + 8*g + 3][p] << 16);
            bu.z = (unsigned)Xs[c0 + 8*g + 4][p] | ((unsigned)Xs[c0 + 8*g + 5][p] << 16);
            bu.w = (unsigned)Xs[c0 + 8*g + 6][p] | ((unsigned)Xs[c0 + 8*g + 7][p] << 16);
            bb[n] = *(bf16x8*)&bu;
        }
        #pragma unroll
        for (int m = 0; m < 4; m++)
            #pragma unroll
            for (int n = 0; n < 4; n++)
                acc[m][n] = __builtin_amdgcn_mfma_f32_16x16x32_bf16(a[m], bb[n], acc[m][n], 0, 0, 0);
    }

    unsigned short* dst = which ? Fk : Eq;
    size_t b8 = (size_t)b * 8;
    #pragma unroll
    for (int m = 0; m < 4; m++) {
        int o0 = 16 * m + 4 * g;
        int hd = o0 >> 3, cp = o0 & 7;
        #pragma unroll
        for (int n = 0; n < 4; n++) {
            int p = p_off + 16 * n + rA;       // = w = kv
            ushort4 pk;
            #pragma unroll
            for (int r = 0; r < 4; r++)
                ((unsigned short*)&pk)[r] = f2bu(acc[m][n][r] + sb[o0 + r]);
            *(ushort4*)(dst + ((b8 + hd) * 256 + p) * 2048 + h * 8 + cp) = pk;
            if (which) {
                #pragma unroll
                for (int r = 0; r < 4; r++) {
                    int o = o0 + r;
                    int d = h * 8 + (o & 7);
                    size_t vbase = (b8 + (size_t)(o >> 3)) * 524288;
                    int idx = (((d >> 4) * 32 + (p >> 3)) << 7) + ((d & 15) << 3) + (p & 7);
                    Fv[vbase + idx] = ((unsigned short*)&pk)[r];
                }
            }
        }
    }
}

// ---------------------------------------------------------------------------
// K4: inverse L2 norms of Q rows and K rows (1 wave per 2048-elem row).
__global__ __launch_bounds__(256) void k_norm(
        const unsigned short* __restrict__ Eq, const unsigned short* __restrict__ Fk,
        float* __restrict__ invQ, float* __restrict__ invK) {
    int lane = threadIdx.x & 63, wid = threadIdx.x >> 6;
    int row = blockIdx.x * 4 + wid;    // 0..16383
    const unsigned short* src = (row < 8192) ? Eq : Fk;
    int r = row & 8191;
    const unsigned short* p = src + (size_t)r * 2048;
    float s = 0.f;
    #pragma unroll
    for (int it = 0; it < 4; it++) {
        uint4 u = *(const uint4*)(p + it * 512 + lane * 8);
        unsigned vals[4] = {u.x, u.y, u.z, u.w};
        #pragma unroll
        for (int e = 0; e < 4; e++) {
            float lo = b2f((unsigned short)(vals[e] & 0xffffu));
            float hi = b2f((unsigned short)(vals[e] >> 16));
            s += lo * lo + hi * hi;
        }
    }
    #pragma unroll
    for (int m = 1; m < 64; m <<= 1) s += __shfl_xor(s, m, 64);
    if (lane == 0) {
        float inv = 1.f / fmaxf(sqrtf(s), 1e-12f);
        (row < 8192 ? invQ : invK)[r] = inv;
    }
}

// ---------------------------------------------------------------------------
// K5a: QK^T partial GEMM, LDS-staged; Sp bf16 (unchanged from R11).
__global__ __launch_bounds__(512) void k_qkt(
        const unsigned short* __restrict__ Eq, const unsigned short* __restrict__ Fk,
        unsigned short* __restrict__ Sp) {
    __shared__ __align__(16) unsigned short KsRaw[256 * 64];
    __shared__ __align__(16) unsigned short QsRaw[32 * 64];
    int bx = blockIdx.x;
    int bh = bx & 31, t2 = bx >> 5;
    int itile = t2 >> 1, ks = t2 & 1;
    int i0 = itile * 32;
    const unsigned short* Qb = Eq + (size_t)bh * 524288 + ks * 1024;
    const unsigned short* Kb = Fk + (size_t)bh * 524288 + ks * 1024;
    int tid = threadIdx.x, lane = tid & 63, wid = tid >> 6;
    int rA = lane & 15, g = lane >> 4;
    int rt = wid & 1, cg = wid >> 1;

    f32x4 acc[4];
    #pragma unroll
    for (int n = 0; n < 4; n++) acc[n] = (f32x4){0.f, 0.f, 0.f, 0.f};

    for (int kc = 0; kc < 1024; kc += 64) {
        #pragma unroll
        for (int it = 0; it < 4; it++) {
            int idx = it * 512 + tid;
            int row = idx >> 3, c8 = idx & 7;
            *(uint4*)&KsRaw[row * 64 + ((c8 ^ (row & 7)) << 3)] =
                *(const uint4*)(Kb + (size_t)row * 2048 + kc + c8 * 8);
        }
        if (tid < 256) {
            int row = tid >> 3, c8 = tid & 7;
            *(uint4*)&QsRaw[row * 64 + ((c8 ^ (row & 7)) << 3)] =
                *(const uint4*)(Qb + (size_t)(i0 + row) * 2048 + kc + c8 * 8);
        }
        __syncthreads();
        #pragma unroll
        for (int kk = 0; kk < 2; kk++) {
            int c8 = kk * 4 + g;
            int arow = rt * 16 + rA;
            bf16x8 a = *(const bf16x8*)&QsRaw[arow * 64 + ((c8 ^ (arow & 7)) << 3)];
            #pragma unroll
            for (int n = 0; n < 4; n++) {
                int brow = cg * 64 + n * 16 + rA;
                bf16x8 b = *(const bf16x8*)&KsRaw[brow * 64 + ((c8 ^ (brow & 7)) << 3)];
                acc[n] = __builtin_amdgcn_mfma_f32_16x16x32_bf16(a, b, acc[n], 0, 0, 0);
            }
        }
        __syncthreads();
    }
    unsigned short* Sb = Sp + (size_t)(ks * 32 + bh) * 65536 + (size_t)i0 * 256;
    #pragma unroll
    for (int n = 0; n < 4; n++)
        #pragma unroll
        for (int r = 0; r < 4; r++)
            Sb[(rt * 16 + g * 4 + r) * 256 + cg * 64 + n * 16 + rA] = f2bu(acc[n][r]);
}

// ---------------------------------------------------------------------------
// K5b: softmax; Sp bf16 (unchanged from R11).
__global__ __launch_bounds__(256) void k_smx(
        const unsigned short* __restrict__ Sp, const float* __restrict__ invQ,
        const float* __restrict__ invK, unsigned short* __restrict__ P) {
    __shared__ float sKv[256];
    int bx = blockIdx.x;
    int bh = bx & 31, rg = bx >> 5;
    int tid = threadIdx.x;
    sKv[tid] = invK[bh * 256 + tid];
    __syncthreads();
    int lr = tid >> 5, sub = tid & 31;
    int i = rg * 8 + lr;
    int R = bh * 256 + i;
    const unsigned short* p0 = Sp + (size_t)bh * 65536 + i * 256;
    const unsigned short* p1 = Sp + (size_t)(32 + bh) * 65536 + i * 256;
    float qs = invQ[R];
    int c0 = sub * 8;
    uint4 ua = *(const uint4*)(p0 + c0);
    uint4 ub = *(const uint4*)(p1 + c0);
    unsigned va[4] = {ua.x, ua.y, ua.z, ua.w};
    unsigned vb[4] = {ub.x, ub.y, ub.z, ub.w};
    float v[8];
    #pragma unroll
    for (int e = 0; e < 4; e++) {
        float alo, ahi, blo, bhi;
        up2(va[e], alo, ahi);
        up2(vb[e], blo, bhi);
        v[2*e]   = alo + blo;
        v[2*e+1] = ahi + bhi;
    }
    float m = -1e30f;
    #pragma unroll
    for (int e = 0; e < 8; e++) {
        v[e] *= qs * sKv[c0 + e];
        m = fmaxf(m, v[e]);
    }
    #pragma unroll
    for (int msk = 1; msk < 32; msk <<= 1) m = fmaxf(m, __shfl_xor(m, msk, 32));
    float s = 0.f;
    #pragma unroll
    for (int e = 0; e < 8; e++) { v[e] = __expf(v[e] - m); s += v[e]; }
    #pragma unroll
    for (int msk = 1; msk < 32; msk <<= 1) s += __shfl_xor(s, msk, 32);
    float inv = 1.f / s;
    uint4 w;
    w.x = (unsigned)f2bu(v[0] * inv) | ((unsigned)f2bu(v[1] * inv) << 16);
    w.y = (unsigned)f2bu(v[2] * inv) | ((unsigned)f2bu(v[3] * inv) << 16);
    w.z = (unsigned)f2bu(v[4] * inv) | ((unsigned)f2bu(v[5] * inv) << 16);
    w.w = (unsigned)f2bu(v[6] * inv) | ((unsigned)f2bu(v[7] * inv) << 16);
    *(uint4*)(P + (size_t)R * 256 + c0) = w;
}

// ---------------------------------------------------------------------------
// K5c: PV + Qn -> out4 NCHW (unchanged).
__global__ __launch_bounds__(512, 4) void k_pv(
        const unsigned short* __restrict__ P, const unsigned short* __restrict__ Fv,
        const unsigned short* __restrict__ Eq, const float* __restrict__ invQ,
        unsigned short* __restrict__ G) {
    __shared__ __align__(16) unsigned short Pb[32][256];
    __shared__ __align__(16) unsigned short Qs[32][1024];
    __shared__ float sQ[32];
    int bx = blockIdx.x;
    int bh = bx & 31, t2 = bx >> 5;
    int itile = t2 >> 1, ds = t2 & 1;
    int i0 = itile * 32;
    int b = bh >> 3, hd = bh & 7;
    const unsigned short* Vt = Fv + (size_t)bh * 524288;
    int tid = threadIdx.x, lane = tid & 63, wid = tid >> 6;
    for (int i = tid; i < 1024; i += 512) {
        int r = i >> 5, cu = i & 31;
        uint4 u = *(const uint4*)(P + (size_t)(bh * 256 + i0 + r) * 256 + cu * 8);
        int su = cu ^ (r & 7);
        *(uint4*)&Pb[r][su * 8] = u;
    }
    for (int i = tid; i < 4096; i += 512) {
        int r = i >> 7, cu = i & 127;
        *(uint4*)&Qs[r][cu * 8] =
            *(const uint4*)(Eq + (size_t)(bh * 256 + i0 + r) * 2048 + ds * 1024 + cu * 8);
    }
    if (tid < 32) sQ[tid] = invQ[bh * 256 + i0 + tid];
    __syncthreads();

    int rA = lane & 15, g = lane >> 4;

    bf16x8 pa[2][8];
    #pragma unroll
    for (int ib = 0; ib < 2; ib++)
        #pragma unroll
        for (int ksl = 0; ksl < 8; ksl++) {
            int rr = ib * 16 + rA;
            int unit = (ksl * 4 + g) ^ (rr & 7);
            pa[ib][ksl] = *(const bf16x8*)&Pb[rr][unit * 8];
        }

    int dloc = wid * 128;
    for (int dt = 0; dt < 8; dt++) {
        int dl = dloc + dt * 16;
        int d0 = ds * 1024 + dl;
        int D = d0 >> 4;
        bf16x8 vb[8];
        #pragma unroll
        for (int ksl = 0; ksl < 8; ksl++)
            vb[ksl] = *(const bf16x8*)&Vt[(size_t)(D * 32 + ksl * 4 + g) * 128 + rA * 8];
        f32x4 o0 = {0.f, 0.f, 0.f, 0.f}, o1 = {0.f, 0.f, 0.f, 0.f};
        #pragma unroll
        for (int ksl = 0; ksl < 8; ksl++) {
            o0 = __builtin_amdgcn_mfma_f32_16x16x32_bf16(pa[0][ksl], vb[ksl], o0, 0, 0, 0);
            o1 = __builtin_amdgcn_mfma_f32_16x16x32_bf16(pa[1][ksl], vb[ksl], o1, 0, 0, 0);
        }
        int d = d0 + rA;
        int dlr = dl + rA;
        int cpr = d & 7, hh = d >> 3;
        #pragma unroll
        for (int ib = 0; ib < 2; ib++) {
            f32x4 oa = ib ? o1 : o0;
            int ibase = i0 + ib * 16 + g * 4;
            ushort4 pk;
            #pragma unroll
            for (int r = 0; r < 4; r++) {
                int il = ib * 16 + g * 4 + r;
                float qv = b2f(Qs[il][dlr]) * sQ[il];
                ((unsigned short*)&pk)[r] = f2bu(oa[r] + qv);
            }
            *(ushort4*)(G + (size_t)(b * 64 + hd * 8 + cpr) * HW + hh * 256 + ibase) = pk;
        }
    }
}

// ---------------------------------------------------------------------------
// K6: out = PW(out4) + S12 (precomputed x1n+x2n). MFMA for PW (unchanged).
__global__ __launch_bounds__(256) void k_final(
        const unsigned short* __restrict__ G, const unsigned short* __restrict__ S12g,
        const float* __restrict__ wpw, const float* __restrict__ bpw,
        float* __restrict__ out) {
    __shared__ __align__(16) unsigned short Ws[64][72];
    __shared__ __align__(16) unsigned short Gs[64][260];
    __shared__ __align__(16) unsigned short S12[64][260];
    __shared__ float sb[64];
    int tid = threadIdx.x;
    for (int i = tid; i < 4096; i += 256) Ws[i >> 6][i & 63] = f2bu(wpw[i]);
    if (tid < 64) sb[tid] = bpw[tid];
    int bx = blockIdx.x, b = bx >> 8, h = bx & 255;
    const unsigned short* src = G + (size_t)b * 64 * HW + h * 256;
    const unsigned short* ssrc = S12g + (size_t)b * 64 * HW + h * 256;
    for (int i = tid; i < 2048; i += 256) {
        int c = i >> 5, ch = i & 31;
        uint4 u = *(const uint4*)(src + (size_t)c * HW + ch * 8);
        *(uint2*)&Gs[c][ch * 8]     = make_uint2(u.x, u.y);
        *(uint2*)&Gs[c][ch * 8 + 4] = make_uint2(u.z, u.w);
        uint4 v = *(const uint4*)(ssrc + (size_t)c * HW + ch * 8);
        *(uint2*)&S12[c][ch * 8]     = make_uint2(v.x, v.y);
        *(uint2*)&S12[c][ch * 8 + 4] = make_uint2(v.z, v.w);
    }
    __syncthreads();

    int lane = tid & 63, wv = tid >> 6;
    int rA = lane & 15, g = lane >> 4;
    int p_off = wv * 64;

    f32x4 acc[4][4];
    #pragma unroll
    for (int m = 0; m < 4; m++)
        #pragma unroll
        for (int n = 0; n < 4; n++) acc[m][n] = (f32x4){0.f, 0.f, 0.f, 0.f};

    #pragma unroll
    for (int ks = 0; ks < 2; ks++) {
        int c0 = ks * 32;
        bf16x8 a[4], bb[4];
        #pragma unroll
        for (int m = 0; m < 4; m++)
            a[m] = *(const bf16x8*)&Ws[16 * m + rA][c0 + 8 * g];
        #pragma unroll
        for (int n = 0; n < 4; n++) {
            int p = p_off + 16 * n + rA;
            uint4 bu;
            bu.x = (unsigned)Gs[c0 + 8*g + 0][p] | ((unsigned)Gs[c0 + 8*g + 1][p] << 16);
            bu.y = (unsigned)Gs[c0 + 8*g + 2][p] | ((unsigned)Gs[c0 + 8*g + 3][p] << 16);
            bu.z = (unsigned)Gs[c0 + 8*g + 4][p] | ((unsigned)Gs[c0 + 8*g + 5][p] << 16);
            bu.w = (unsigned)Gs[c0 + 8*g + 6][p] | ((unsigned)Gs[c0 + 8*g + 7][p] << 16);
            bb[n] = *(bf16x8*)&bu;
        }
        #pragma unroll
        for (int m = 0; m < 4; m++)
            #pragma unroll
            for (int n = 0; n < 4; n++)
                acc[m][n] = __builtin_amdgcn_mfma_f32_16x16x32_bf16(a[m], bb[n], acc[m][n], 0, 0, 0);
    }

    #pragma unroll
    for (int m = 0; m < 4; m++) {
        int o0 = 16 * m + 4 * g;
        #pragma unroll
        for (int n = 0; n < 4; n++) {
            int p = p_off + 16 * n + rA;
            #pragma unroll
            for (int r = 0; r < 4; r++) {
                int o = o0 + r;
                out[(size_t)(b * 64 + o) * HW + h * 256 + p] =
                    acc[m][n][r] + sb[o] + b2f(S12[o][p]);
            }
        }
    }
}

// ---------------------------------------------------------------------------
extern "C" void kernel_launch(void* const* d_in, const int* in_sizes, int n_in,
                              void* d_out, int out_size, void* d_ws, size_t ws_size,
                              hipStream_t stream) {
    const float* x1   = (const float*)d_in[0];
    const float* x2   = (const float*)d_in[1];
    const float* ln1w = (const float*)d_in[2];
    const float* ln1b = (const float*)d_in[3];
    const float* ln2w = (const float*)d_in[4];
    const float* ln2b = (const float*)d_in[5];
    const float* bdw  = (const float*)d_in[6];
    const float* wpw  = (const float*)d_in[7];
    const float* bpw  = (const float*)d_in[8];
    const float* kk[12];
    for (int i = 0; i < 12; i++) kk[i] = (const float*)d_in[9 + i];

    char* ws = (char*)d_ws;
    float* wcomb = (float*)ws;              // 5376 floats
    float* bias  = (float*)(ws + 21504);    // 128 floats
    float* invQ  = (float*)(ws + 32768);    // 8192 floats
    float* invK  = (float*)(ws + 65536);    // 8192 floats
    const size_t SMALL = 131072;
    const size_t SZ = 33554432;             // 32 MiB = 16.7M bf16 elements

    unsigned short* S12b = (unsigned short*)(ws + SMALL);
    unsigned short* S1 = (unsigned short*)(ws + SMALL + SZ);
    unsigned short* S2 = (unsigned short*)(ws + SMALL + 2 * SZ);
    unsigned short* S3 = (unsigned short*)(ws + SMALL + 3 * SZ);
    unsigned short* dw1 = (unsigned short*)d_out;
    unsigned short* dw2 = dw1 + SZ / 2;     // element offset = 16.7M
    unsigned short* Sp = (unsigned short*)d_out;                     // 8.4 MB bf16
    unsigned short* P = (unsigned short*)((char*)d_out + 20971520);  // 4.2 MB

    k_prep<<<1, 64, 0, stream>>>(kk[0], kk[1], kk[2], kk[3], kk[4], kk[5],
                                 kk[6], kk[7], kk[8], kk[9], kk[10], kk[11],
                                 bdw, wcomb, bias);
    k_ln<<<2048, 128, 0, stream>>>(x1, x2, ln1w, ln1b, ln2w, ln2b, S1, S2, S12b);
    k_dw<<<dim3(2048, 2), 256, 0, stream>>>(S1, S2, wcomb, bias, dw1, dw2);
    k_pw<<<dim3(1024, 2), 256, 0, stream>>>(dw1, dw2, wpw, bpw, S1, S2, S3);
    k_norm<<<4096, 256, 0, stream>>>(S1, S2, invQ, invK);
    k_qkt<<<512, 512, 0, stream>>>(S1, S2, Sp);
    k_smx<<<1024, 256, 0, stream>>>(Sp, invQ, invK, P);
    k_pv<<<512, 512, 0, stream>>>(P, S3, S1, invQ, S2);
    k_final<<<1024, 256, 0, stream>>>(S2, S12b, wpw, bpw, (float*)d_out);
}

// Round 13
// 261.709 us; speedup vs baseline: 1.5357x; 1.5357x over previous
//
#include <hip/hip_runtime.h>

#define HW 65536  // 256*256

typedef __bf16 bf16x8 __attribute__((ext_vector_type(8)));
typedef float f32x4 __attribute__((ext_vector_type(4)));

__device__ __forceinline__ float b2f(unsigned short u) {
    return __uint_as_float(((unsigned)u) << 16);
}
__device__ __forceinline__ unsigned short f2bu(float f) {
    unsigned u = __float_as_uint(f);
    return (unsigned short)((u + 0x7FFFu + ((u >> 16) & 1u)) >> 16);
}
// unpack a u32 holding 2 bf16 -> 2 floats (1 VALU op each)
__device__ __forceinline__ void up2(unsigned u, float& lo, float& hi) {
    lo = __uint_as_float(u << 16);
    hi = __uint_as_float(u & 0xFFFF0000u);
}

// ---------------------------------------------------------------------------
// K0: fold 6 depthwise kernels -> combined 21-tap h + 21-tap v per tensor.
__global__ void k_prep(const float* k11, const float* k12, const float* k13,
                       const float* k14, const float* k15, const float* k16,
                       const float* k21, const float* k22, const float* k23,
                       const float* k24, const float* k25, const float* k26,
                       const float* bdw, float* wcomb, float* bias) {
    int c = threadIdx.x;
    if (c >= 64) return;
    float* wh1 = wcomb;
    float* wv1 = wcomb + 1344;
    float* wh2 = wcomb + 2688;
    float* wv2 = wcomb + 4032;
    for (int j = 0; j < 21; j++) {
        wh1[c*21+j] = k13[c*21+j];
        wv1[c*21+j] = k16[c*21+j];
        wh2[c*21+j] = k23[c*21+j];
        wv2[c*21+j] = k26[c*21+j];
    }
    for (int j = 0; j < 11; j++) {
        wh1[c*21+j+5] += k12[c*11+j];
        wv1[c*21+j+5] += k15[c*11+j];
        wh2[c*21+j+5] += k22[c*11+j];
        wv2[c*21+j+5] += k25[c*11+j];
    }
    for (int j = 0; j < 7; j++) {
        wh1[c*21+j+7] += k11[c*7+j];
        wv1[c*21+j+7] += k14[c*7+j];
        wh2[c*21+j+7] += k21[c*7+j];
        wv2[c*21+j+7] += k24[c*7+j];
    }
    float s1 = 0.f, s2 = 0.f;
    for (int i = 0; i < 6; i++) { s1 += bdw[i*64+c]; s2 += bdw[(6+i)*64+c]; }
    bias[c] = s1; bias[64+c] = s2;
}

// ---------------------------------------------------------------------------
// K1: per-pixel LayerNorm of BOTH tensors + S12 = x1n + x2n (bf16).
// R10 version (known-good codegen: VGPR 76, ~60-66 us). Do not restructure:
// two-pass variants (R11 float2 / R12 barrier) both ballooned to 224-256
// VGPR via compiler pass-fusion/pipelining and ran 3x slower.
__global__ __launch_bounds__(256) void k_ln(
        const float* __restrict__ x1, const float* __restrict__ x2,
        const float* __restrict__ w1, const float* __restrict__ b1,
        const float* __restrict__ w2, const float* __restrict__ b2,
        unsigned short* __restrict__ o1, unsigned short* __restrict__ o2,
        unsigned short* __restrict__ s12) {
    int p = blockIdx.x * 256 + threadIdx.x;   // 0..262143
    int b = p >> 16, hw = p & (HW - 1);
    size_t base = (size_t)b * 64 * HW + hw;
    float v[64];
    unsigned n1[32];
    {
        float s = 0.f;
        #pragma unroll
        for (int c = 0; c < 64; c++) { v[c] = x1[base + (size_t)c * HW]; s += v[c]; }
        float mu = s * 0.015625f, s2 = 0.f;
        #pragma unroll
        for (int c = 0; c < 64; c++) { float d = v[c] - mu; s2 += d * d; }
        float rstd = rsqrtf(s2 * 0.015625f + 1e-5f);
        #pragma unroll
        for (int c2 = 0; c2 < 32; c2++) {
            unsigned short lo = f2bu((v[2*c2]   - mu) * rstd * w1[2*c2]   + b1[2*c2]);
            unsigned short hi = f2bu((v[2*c2+1] - mu) * rstd * w1[2*c2+1] + b1[2*c2+1]);
            o1[base + (size_t)(2*c2)   * HW] = lo;
            o1[base + (size_t)(2*c2+1) * HW] = hi;
            n1[c2] = (unsigned)lo | ((unsigned)hi << 16);
        }
    }
    {
        float s = 0.f;
        #pragma unroll
        for (int c = 0; c < 64; c++) { v[c] = x2[base + (size_t)c * HW]; s += v[c]; }
        float mu = s * 0.015625f, s2 = 0.f;
        #pragma unroll
        for (int c = 0; c < 64; c++) { float d = v[c] - mu; s2 += d * d; }
        float rstd = rsqrtf(s2 * 0.015625f + 1e-5f);
        #pragma unroll
        for (int c2 = 0; c2 < 32; c2++) {
            float a2 = (v[2*c2]   - mu) * rstd * w2[2*c2]   + b2[2*c2];
            float b2n = (v[2*c2+1] - mu) * rstd * w2[2*c2+1] + b2[2*c2+1];
            o2[base + (size_t)(2*c2)   * HW] = f2bu(a2);
            o2[base + (size_t)(2*c2+1) * HW] = f2bu(b2n);
            float lo, hi;
            up2(n1[c2], lo, hi);
            s12[base + (size_t)(2*c2)   * HW] = f2bu(lo + a2);
            s12[base + (size_t)(2*c2+1) * HW] = f2bu(hi + b2n);
        }
    }
}

// ---------------------------------------------------------------------------
// K2: combined depthwise conv via MFMA Toeplitz (unchanged).
__global__ __launch_bounds__(256) void k_dw(
        const unsigned short* __restrict__ in1, const unsigned short* __restrict__ in2,
        const float* __restrict__ wcomb, const float* __restrict__ bias,
        unsigned short* __restrict__ o1, unsigned short* __restrict__ o2) {
    __shared__ __align__(16) unsigned short tileRaw[52 * 320];
    __shared__ __align__(16) unsigned short ThT[16][64];
    __shared__ __align__(16) unsigned short TvA[16][64];
    int which = blockIdx.y;
    const unsigned short* in = which ? in2 : in1;
    unsigned short* o = which ? o2 : o1;
    int bx = blockIdx.x;
    int bc = bx >> 3, tileid = bx & 7;
    int c = bc & 63;
    int h0 = tileid * 32;
    int tid = threadIdx.x;

    {
        const float* whp = wcomb + which * 2688 + c * 21;
        const float* wvp = whp + 1344;
        for (int i = tid; i < 2048; i += 256) {
            int mat = i >> 10;
            int idx = i & 1023;
            int n = idx >> 6, k = idx & 63;
            int j = k - n - 6;
            float v = (j >= 0 && j < 21) ? (mat ? wvp[j] : whp[j]) : 0.f;
            (mat ? &TvA[0][0] : &ThT[0][0])[idx] = f2bu(v);
        }
    }
    const unsigned short* src = in + (size_t)bc * HW;
    for (int idx = tid; idx < 52 * 40; idx += 256) {
        int row = idx / 40, u = idx - row * 40;
        int grow = h0 - 10 + row;
        uint4 val = make_uint4(0u, 0u, 0u, 0u);
        if ((unsigned)grow < 256u && u >= 2 && u < 34)
            val = *(const uint4*)(src + grow * 256 + (u - 2) * 8);
        *(uint4*)&tileRaw[row * 320 + ((u ^ ((row >> 1) & 7)) << 3)] = val;
    }
    float bs = bias[which * 64 + c];
    __syncthreads();

    int lane = tid & 63, wid = tid >> 6;
    int rA = lane & 15, g = lane >> 4, kf = g * 8;

    bf16x8 thB0 = *(const bf16x8*)&ThT[rA][kf];
    bf16x8 thB1 = *(const bf16x8*)&ThT[rA][32 + kf];
    bf16x8 tvA0 = *(const bf16x8*)&TvA[rA][kf];
    bf16x8 tvA1 = *(const bf16x8*)&TvA[rA][32 + kf];

    int ht = wid & 1, wgrp = wid >> 1;
    for (int t = 0; t < 8; t++) {
        int w0 = (wgrp * 8 + t) * 16;
        int ub = w0 >> 3;
        int hrow = ht * 16 + rA + 10;
        int xh = (hrow >> 1) & 7;
        bf16x8 ax0 = *(const bf16x8*)&tileRaw[hrow * 320 + (((ub + g) ^ xh) << 3)];
        bf16x8 ax1 = *(const bf16x8*)&tileRaw[hrow * 320 + (((ub + 4 + g) ^ xh) << 3)];
        int uvb = ub + 2 + (rA >> 3);
        int el = rA & 7;
        uint4 bv0, bv1;
        unsigned* pv0 = (unsigned*)&bv0;
        unsigned* pv1 = (unsigned*)&bv1;
        #pragma unroll
        for (int e2 = 0; e2 < 4; e2++) {
            int k0i = kf + 2 * e2;
            int r0 = ht * 16 + k0i - 6;  r0 = r0 < 0 ? 0 : (r0 > 51 ? 51 : r0);
            int r1 = ht * 16 + k0i - 5;  r1 = r1 < 0 ? 0 : (r1 > 51 ? 51 : r1);
            unsigned lo = tileRaw[r0 * 320 + ((uvb ^ ((r0 >> 1) & 7)) << 3) + el];
            unsigned hi = tileRaw[r1 * 320 + ((uvb ^ ((r1 >> 1) & 7)) << 3) + el];
            pv0[e2] = lo | (hi << 16);
            int k1i = 32 + kf + 2 * e2;
            int r2 = ht * 16 + k1i - 6;  r2 = r2 < 0 ? 0 : (r2 > 51 ? 51 : r2);
            int r3 = ht * 16 + k1i - 5;  r3 = r3 < 0 ? 0 : (r3 > 51 ? 51 : r3);
            unsigned lo2 = tileRaw[r2 * 320 + ((uvb ^ ((r2 >> 1) & 7)) << 3) + el];
            unsigned hi2 = tileRaw[r3 * 320 + ((uvb ^ ((r3 >> 1) & 7)) << 3) + el];
            pv1[e2] = lo2 | (hi2 << 16);
        }
        f32x4 acc = {bs, bs, bs, bs};
        acc = __builtin_amdgcn_mfma_f32_16x16x32_bf16(ax0, thB0, acc, 0, 0, 0);
        acc = __builtin_amdgcn_mfma_f32_16x16x32_bf16(ax1, thB1, acc, 0, 0, 0);
        acc = __builtin_amdgcn_mfma_f32_16x16x32_bf16(tvA0, *(bf16x8*)&bv0, acc, 0, 0, 0);
        acc = __builtin_amdgcn_mfma_f32_16x16x32_bf16(tvA1, *(bf16x8*)&bv1, acc, 0, 0, 0);
        int wc = w0 + rA;
        size_t obase = (size_t)bc * HW + wc;
        #pragma unroll
        for (int r = 0; r < 4; r++) {
            int hh = h0 + ht * 16 + 4 * g + r;
            o[obase + (size_t)hh * 256] = f2bu(acc[r]);
        }
    }
}

// ---------------------------------------------------------------------------
// K3: 1x1 conv (64x64), MFMA, kv-tiled V layout (unchanged).
__global__ __launch_bounds__(256) void k_pw(
        const unsigned short* __restrict__ in1, const unsigned short* __restrict__ in2,
        const float* __restrict__ wpw, const float* __restrict__ bpw,
        unsigned short* __restrict__ Eq, unsigned short* __restrict__ Fk,
        unsigned short* __restrict__ Fv) {
    __shared__ __align__(16) unsigned short Ws[64][72];
    __shared__ __align__(16) unsigned short Xs[64][260];
    __shared__ float sb[64];
    int tid = threadIdx.x;
    for (int i = tid; i < 4096; i += 256) Ws[i >> 6][i & 63] = f2bu(wpw[i]);
    if (tid < 64) sb[tid] = bpw[tid];
    int which = blockIdx.y;
    const unsigned short* in = which ? in2 : in1;
    int bx = blockIdx.x;
    int b = bx & 3;
    int h = ((bx >> 2) & 31) * 8 + (bx >> 7);
    const unsigned short* src = in + (size_t)b * 64 * HW + h * 256;
    for (int i = tid; i < 2048; i += 256) {
        int c = i >> 5, ch = i & 31;
        uint4 u = *(const uint4*)(src + (size_t)c * HW + ch * 8);
        *(uint2*)&Xs[c][ch * 8]     = make_uint2(u.x, u.y);
        *(uint2*)&Xs[c][ch * 8 + 4] = make_uint2(u.z, u.w);
    }
    __syncthreads();

    int lane = tid & 63, wv = tid >> 6;
    int rA = lane & 15, g = lane >> 4;
    int p_off = wv * 64;

    f32x4 acc[4][4];
    #pragma unroll
    for (int m = 0; m < 4; m++)
        #pragma unroll
        for (int n = 0; n < 4; n++) acc[m][n] = (f32x4){0.f, 0.f, 0.f, 0.f};

    #pragma unroll
    for (int ks = 0; ks < 2; ks++) {
        int c0 = ks * 32;
        bf16x8 a[4], bb[4];
        #pragma unroll
        for (int m = 0; m < 4; m++)
            a[m] = *(const bf16x8*)&Ws[16 * m + rA][c0 + 8 * g];
        #pragma unroll
        for (int n = 0; n < 4; n++) {
            int p = p_off + 16 * n + rA;
            uint4 bu;
            bu.x = (unsigned)Xs[c0 + 8*g + 0][p] | ((unsigned)Xs[c0 + 8*g + 1][p] << 16);
            bu.y = (unsigned)Xs[c0 + 8*g + 2][p] | ((unsigned)Xs[c0 + 8*g + 3][p] << 16);
            bu.z = (unsigned)Xs[c0 + 8*g + 4][p] | ((unsigned)Xs[c0 + 8*g + 5][p] << 16);
            bu.w = (unsigned)Xs[c0 + 8*g + 6][p] | ((unsigned)Xs[c0 + 8*g + 7][p] << 16);
            bb[n] = *(bf16x8*)&bu;
        }
        #pragma unroll
        for (int m = 0; m < 4; m++)
            #pragma unroll
            for (int n = 0; n < 4; n++)
                acc[m][n] = __builtin_amdgcn_mfma_f32_16x16x32_bf16(a[m], bb[n], acc[m][n], 0, 0, 0);
    }

    unsigned short* dst = which ? Fk : Eq;
    size_t b8 = (size_t)b * 8;
    #pragma unroll
    for (int m = 0; m < 4; m++) {
        int o0 = 16 * m + 4 * g;
        int hd = o0 >> 3, cp = o0 & 7;
        #pragma unroll
        for (int n = 0; n < 4; n++) {
            int p = p_off + 16 * n + rA;       // = w = kv
            ushort4 pk;
            #pragma unroll
            for (int r = 0; r < 4; r++)
                ((unsigned short*)&pk)[r] = f2bu(acc[m][n][r] + sb[o0 + r]);
            *(ushort4*)(dst + ((b8 + hd) * 256 + p) * 2048 + h * 8 + cp) = pk;
            if (which) {
                #pragma unroll
                for (int r = 0; r < 4; r++) {
                    int o = o0 + r;
                    int d = h * 8 + (o & 7);
                    size_t vbase = (b8 + (size_t)(o >> 3)) * 524288;
                    int idx = (((d >> 4) * 32 + (p >> 3)) << 7) + ((d & 15) << 3) + (p & 7);
                    Fv[vbase + idx] = ((unsigned short*)&pk)[r];
                }
            }
        }
    }
}

// ---------------------------------------------------------------------------
// K4: inverse L2 norms of Q rows and K rows (1 wave per 2048-elem row).
__global__ __launch_bounds__(256) void k_norm(
        const unsigned short* __restrict__ Eq, const unsigned short* __restrict__ Fk,
        float* __restrict__ invQ, float* __restrict__ invK) {
    int lane = threadIdx.x & 63, wid = threadIdx.x >> 6;
    int row = blockIdx.x * 4 + wid;    // 0..16383
    const unsigned short* src = (row < 8192) ? Eq : Fk;
    int r = row & 8191;
    const unsigned short* p = src + (size_t)r * 2048;
    float s = 0.f;
    #pragma unroll
    for (int it = 0; it < 4; it++) {
        uint4 u = *(const uint4*)(p + it * 512 + lane * 8);
        unsigned vals[4] = {u.x, u.y, u.z, u.w};
        #pragma unroll
        for (int e = 0; e < 4; e++) {
            float lo = b2f((unsigned short)(vals[e] & 0xffffu));
            float hi = b2f((unsigned short)(vals[e] >> 16));
            s += lo * lo + hi * hi;
        }
    }
    #pragma unroll
    for (int m = 1; m < 64; m <<= 1) s += __shfl_xor(s, m, 64);
    if (lane == 0) {
        float inv = 1.f / fmaxf(sqrtf(s), 1e-12f);
        (row < 8192 ? invQ : invK)[r] = inv;
    }
}

// ---------------------------------------------------------------------------
// K5a: QK^T partial GEMM, LDS-staged; Sp bf16 (unchanged).
__global__ __launch_bounds__(512) void k_qkt(
        const unsigned short* __restrict__ Eq, const unsigned short* __restrict__ Fk,
        unsigned short* __restrict__ Sp) {
    __shared__ __align__(16) unsigned short KsRaw[256 * 64];
    __shared__ __align__(16) unsigned short QsRaw[32 * 64];
    int bx = blockIdx.x;
    int bh = bx & 31, t2 = bx >> 5;
    int itile = t2 >> 1, ks = t2 & 1;
    int i0 = itile * 32;
    const unsigned short* Qb = Eq + (size_t)bh * 524288 + ks * 1024;
    const unsigned short* Kb = Fk + (size_t)bh * 524288 + ks * 1024;
    int tid = threadIdx.x, lane = tid & 63, wid = tid >> 6;
    int rA = lane & 15, g = lane >> 4;
    int rt = wid & 1, cg = wid >> 1;

    f32x4 acc[4];
    #pragma unroll
    for (int n = 0; n < 4; n++) acc[n] = (f32x4){0.f, 0.f, 0.f, 0.f};

    for (int kc = 0; kc < 1024; kc += 64) {
        #pragma unroll
        for (int it = 0; it < 4; it++) {
            int idx = it * 512 + tid;
            int row = idx >> 3, c8 = idx & 7;
            *(uint4*)&KsRaw[row * 64 + ((c8 ^ (row & 7)) << 3)] =
                *(const uint4*)(Kb + (size_t)row * 2048 + kc + c8 * 8);
        }
        if (tid < 256) {
            int row = tid >> 3, c8 = tid & 7;
            *(uint4*)&QsRaw[row * 64 + ((c8 ^ (row & 7)) << 3)] =
                *(const uint4*)(Qb + (size_t)(i0 + row) * 2048 + kc + c8 * 8);
        }
        __syncthreads();
        #pragma unroll
        for (int kk = 0; kk < 2; kk++) {
            int c8 = kk * 4 + g;
            int arow = rt * 16 + rA;
            bf16x8 a = *(const bf16x8*)&QsRaw[arow * 64 + ((c8 ^ (arow & 7)) << 3)];
            #pragma unroll
            for (int n = 0; n < 4; n++) {
                int brow = cg * 64 + n * 16 + rA;
                bf16x8 b = *(const bf16x8*)&KsRaw[brow * 64 + ((c8 ^ (brow & 7)) << 3)];
                acc[n] = __builtin_amdgcn_mfma_f32_16x16x32_bf16(a, b, acc[n], 0, 0, 0);
            }
        }
        __syncthreads();
    }
    unsigned short* Sb = Sp + (size_t)(ks * 32 + bh) * 65536 + (size_t)i0 * 256;
    #pragma unroll
    for (int n = 0; n < 4; n++)
        #pragma unroll
        for (int r = 0; r < 4; r++)
            Sb[(rt * 16 + g * 4 + r) * 256 + cg * 64 + n * 16 + rA] = f2bu(acc[n][r]);
}

// ---------------------------------------------------------------------------
// K5b: softmax; Sp bf16 (unchanged).
__global__ __launch_bounds__(256) void k_smx(
        const unsigned short* __restrict__ Sp, const float* __restrict__ invQ,
        const float* __restrict__ invK, unsigned short* __restrict__ P) {
    __shared__ float sKv[256];
    int bx = blockIdx.x;
    int bh = bx & 31, rg = bx >> 5;
    int tid = threadIdx.x;
    sKv[tid] = invK[bh * 256 + tid];
    __syncthreads();
    int lr = tid >> 5, sub = tid & 31;
    int i = rg * 8 + lr;
    int R = bh * 256 + i;
    const unsigned short* p0 = Sp + (size_t)bh * 65536 + i * 256;
    const unsigned short* p1 = Sp + (size_t)(32 + bh) * 65536 + i * 256;
    float qs = invQ[R];
    int c0 = sub * 8;
    uint4 ua = *(const uint4*)(p0 + c0);
    uint4 ub = *(const uint4*)(p1 + c0);
    unsigned va[4] = {ua.x, ua.y, ua.z, ua.w};
    unsigned vb[4] = {ub.x, ub.y, ub.z, ub.w};
    float v[8];
    #pragma unroll
    for (int e = 0; e < 4; e++) {
        float alo, ahi, blo, bhi;
        up2(va[e], alo, ahi);
        up2(vb[e], blo, bhi);
        v[2*e]   = alo + blo;
        v[2*e+1] = ahi + bhi;
    }
    float m = -1e30f;
    #pragma unroll
    for (int e = 0; e < 8; e++) {
        v[e] *= qs * sKv[c0 + e];
        m = fmaxf(m, v[e]);
    }
    #pragma unroll
    for (int msk = 1; msk < 32; msk <<= 1) m = fmaxf(m, __shfl_xor(m, msk, 32));
    float s = 0.f;
    #pragma unroll
    for (int e = 0; e < 8; e++) { v[e] = __expf(v[e] - m); s += v[e]; }
    #pragma unroll
    for (int msk = 1; msk < 32; msk <<= 1) s += __shfl_xor(s, msk, 32);
    float inv = 1.f / s;
    uint4 w;
    w.x = (unsigned)f2bu(v[0] * inv) | ((unsigned)f2bu(v[1] * inv) << 16);
    w.y = (unsigned)f2bu(v[2] * inv) | ((unsigned)f2bu(v[3] * inv) << 16);
    w.z = (unsigned)f2bu(v[4] * inv) | ((unsigned)f2bu(v[5] * inv) << 16);
    w.w = (unsigned)f2bu(v[6] * inv) | ((unsigned)f2bu(v[7] * inv) << 16);
    *(uint4*)(P + (size_t)R * 256 + c0) = w;
}

// ---------------------------------------------------------------------------
// K5c: PV + Qn -> out4 NCHW (unchanged).
__global__ __launch_bounds__(512, 4) void k_pv(
        const unsigned short* __restrict__ P, const unsigned short* __restrict__ Fv,
        const unsigned short* __restrict__ Eq, const float* __restrict__ invQ,
        unsigned short* __restrict__ G) {
    __shared__ __align__(16) unsigned short Pb[32][256];
    __shared__ __align__(16) unsigned short Qs[32][1024];
    __shared__ float sQ[32];
    int bx = blockIdx.x;
    int bh = bx & 31, t2 = bx >> 5;
    int itile = t2 >> 1, ds = t2 & 1;
    int i0 = itile * 32;
    int b = bh >> 3, hd = bh & 7;
    const unsigned short* Vt = Fv + (size_t)bh * 524288;
    int tid = threadIdx.x, lane = tid & 63, wid = tid >> 6;
    for (int i = tid; i < 1024; i += 512) {
        int r = i >> 5, cu = i & 31;
        uint4 u = *(const uint4*)(P + (size_t)(bh * 256 + i0 + r) * 256 + cu * 8);
        int su = cu ^ (r & 7);
        *(uint4*)&Pb[r][su * 8] = u;
    }
    for (int i = tid; i < 4096; i += 512) {
        int r = i >> 7, cu = i & 127;
        *(uint4*)&Qs[r][cu * 8] =
            *(const uint4*)(Eq + (size_t)(bh * 256 + i0 + r) * 2048 + ds * 1024 + cu * 8);
    }
    if (tid < 32) sQ[tid] = invQ[bh * 256 + i0 + tid];
    __syncthreads();

    int rA = lane & 15, g = lane >> 4;

    bf16x8 pa[2][8];
    #pragma unroll
    for (int ib = 0; ib < 2; ib++)
        #pragma unroll
        for (int ksl = 0; ksl < 8; ksl++) {
            int rr = ib * 16 + rA;
            int unit = (ksl * 4 + g) ^ (rr & 7);
            pa[ib][ksl] = *(const bf16x8*)&Pb[rr][unit * 8];
        }

    int dloc = wid * 128;
    for (int dt = 0; dt < 8; dt++) {
        int dl = dloc + dt * 16;
        int d0 = ds * 1024 + dl;
        int D = d0 >> 4;
        bf16x8 vb[8];
        #pragma unroll
        for (int ksl = 0; ksl < 8; ksl++)
            vb[ksl] = *(const bf16x8*)&Vt[(size_t)(D * 32 + ksl * 4 + g) * 128 + rA * 8];
        f32x4 o0 = {0.f, 0.f, 0.f, 0.f}, o1 = {0.f, 0.f, 0.f, 0.f};
        #pragma unroll
        for (int ksl = 0; ksl < 8; ksl++) {
            o0 = __builtin_amdgcn_mfma_f32_16x16x32_bf16(pa[0][ksl], vb[ksl], o0, 0, 0, 0);
            o1 = __builtin_amdgcn_mfma_f32_16x16x32_bf16(pa[1][ksl], vb[ksl], o1, 0, 0, 0);
        }
        int d = d0 + rA;
        int dlr = dl + rA;
        int cpr = d & 7, hh = d >> 3;
        #pragma unroll
        for (int ib = 0; ib < 2; ib++) {
            f32x4 oa = ib ? o1 : o0;
            int ibase = i0 + ib * 16 + g * 4;
            ushort4 pk;
            #pragma unroll
            for (int r = 0; r < 4; r++) {
                int il = ib * 16 + g * 4 + r;
                float qv = b2f(Qs[il][dlr]) * sQ[il];
                ((unsigned short*)&pk)[r] = f2bu(oa[r] + qv);
            }
            *(ushort4*)(G + (size_t)(b * 64 + hd * 8 + cpr) * HW + hh * 256 + ibase) = pk;
        }
    }
}

// ---------------------------------------------------------------------------
// K6: out = PW(out4) + S12 (precomputed x1n+x2n). MFMA for PW (unchanged).
__global__ __launch_bounds__(256) void k_final(
        const unsigned short* __restrict__ G, const unsigned short* __restrict__ S12g,
        const float* __restrict__ wpw, const float* __restrict__ bpw,
        float* __restrict__ out) {
    __shared__ __align__(16) unsigned short Ws[64][72];
    __shared__ __align__(16) unsigned short Gs[64][260];
    __shared__ __align__(16) unsigned short S12[64][260];
    __shared__ float sb[64];
    int tid = threadIdx.x;
    for (int i = tid; i < 4096; i += 256) Ws[i >> 6][i & 63] = f2bu(wpw[i]);
    if (tid < 64) sb[tid] = bpw[tid];
    int bx = blockIdx.x, b = bx >> 8, h = bx & 255;
    const unsigned short* src = G + (size_t)b * 64 * HW + h * 256;
    const unsigned short* ssrc = S12g + (size_t)b * 64 * HW + h * 256;
    for (int i = tid; i < 2048; i += 256) {
        int c = i >> 5, ch = i & 31;
        uint4 u = *(const uint4*)(src + (size_t)c * HW + ch * 8);
        *(uint2*)&Gs[c][ch * 8]     = make_uint2(u.x, u.y);
        *(uint2*)&Gs[c][ch * 8 + 4] = make_uint2(u.z, u.w);
        uint4 v = *(const uint4*)(ssrc + (size_t)c * HW + ch * 8);
        *(uint2*)&S12[c][ch * 8]     = make_uint2(v.x, v.y);
        *(uint2*)&S12[c][ch * 8 + 4] = make_uint2(v.z, v.w);
    }
    __syncthreads();

    int lane = tid & 63, wv = tid >> 6;
    int rA = lane & 15, g = lane >> 4;
    int p_off = wv * 64;

    f32x4 acc[4][4];
    #pragma unroll
    for (int m = 0; m < 4; m++)
        #pragma unroll
        for (int n = 0; n < 4; n++) acc[m][n] = (f32x4){0.f, 0.f, 0.f, 0.f};

    #pragma unroll
    for (int ks = 0; ks < 2; ks++) {
        int c0 = ks * 32;
        bf16x8 a[4], bb[4];
        #pragma unroll
        for (int m = 0; m < 4; m++)
            a[m] = *(const bf16x8*)&Ws[16 * m + rA][c0 + 8 * g];
        #pragma unroll
        for (int n = 0; n < 4; n++) {
            int p = p_off + 16 * n + rA;
            uint4 bu;
            bu.x = (unsigned)Gs[c0 + 8*g + 0][p] | ((unsigned)Gs[c0 + 8*g + 1][p] << 16);
            bu.y = (unsigned)Gs[c0 + 8*g + 2][p] | ((unsigned)Gs[c0 + 8*g + 3][p] << 16);
            bu.z = (unsigned)Gs[c0 + 8*g + 4][p] | ((unsigned)Gs[c0 + 8*g + 5][p] << 16);
            bu.w = (unsigned)Gs[c0 + 8*g + 6][p] | ((unsigned)Gs[c0 + 8*g + 7][p] << 16);
            bb[n] = *(bf16x8*)&bu;
        }
        #pragma unroll
        for (int m = 0; m < 4; m++)
            #pragma unroll
            for (int n = 0; n < 4; n++)
                acc[m][n] = __builtin_amdgcn_mfma_f32_16x16x32_bf16(a[m], bb[n], acc[m][n], 0, 0, 0);
    }

    #pragma unroll
    for (int m = 0; m < 4; m++) {
        int o0 = 16 * m + 4 * g;
        #pragma unroll
        for (int n = 0; n < 4; n++) {
            int p = p_off + 16 * n + rA;
            #pragma unroll
            for (int r = 0; r < 4; r++) {
                int o = o0 + r;
                out[(size_t)(b * 64 + o) * HW + h * 256 + p] =
                    acc[m][n][r] + sb[o] + b2f(S12[o][p]);
            }
        }
    }
}

// ---------------------------------------------------------------------------
extern "C" void kernel_launch(void* const* d_in, const int* in_sizes, int n_in,
                              void* d_out, int out_size, void* d_ws, size_t ws_size,
                              hipStream_t stream) {
    const float* x1   = (const float*)d_in[0];
    const float* x2   = (const float*)d_in[1];
    const float* ln1w = (const float*)d_in[2];
    const float* ln1b = (const float*)d_in[3];
    const float* ln2w = (const float*)d_in[4];
    const float* ln2b = (const float*)d_in[5];
    const float* bdw  = (const float*)d_in[6];
    const float* wpw  = (const float*)d_in[7];
    const float* bpw  = (const float*)d_in[8];
    const float* kk[12];
    for (int i = 0; i < 12; i++) kk[i] = (const float*)d_in[9 + i];

    char* ws = (char*)d_ws;
    float* wcomb = (float*)ws;              // 5376 floats
    float* bias  = (float*)(ws + 21504);    // 128 floats
    float* invQ  = (float*)(ws + 32768);    // 8192 floats
    float* invK  = (float*)(ws + 65536);    // 8192 floats
    const size_t SMALL = 131072;
    const size_t SZ = 33554432;             // 32 MiB = 16.7M bf16 elements

    unsigned short* S12b = (unsigned short*)(ws + SMALL);
    unsigned short* S1 = (unsigned short*)(ws + SMALL + SZ);
    unsigned short* S2 = (unsigned short*)(ws + SMALL + 2 * SZ);
    unsigned short* S3 = (unsigned short*)(ws + SMALL + 3 * SZ);
    unsigned short* dw1 = (unsigned short*)d_out;
    unsigned short* dw2 = dw1 + SZ / 2;     // element offset = 16.7M
    unsigned short* Sp = (unsigned short*)d_out;                     // 8.4 MB bf16
    unsigned short* P = (unsigned short*)((char*)d_out + 20971520);  // 4.2 MB

    k_prep<<<1, 64, 0, stream>>>(kk[0], kk[1], kk[2], kk[3], kk[4], kk[5],
                                 kk[6], kk[7], kk[8], kk[9], kk[10], kk[11],
                                 bdw, wcomb, bias);
    k_ln<<<1024, 256, 0, stream>>>(x1, x2, ln1w, ln1b, ln2w, ln2b, S1, S2, S12b);
    k_dw<<<dim3(2048, 2), 256, 0, stream>>>(S1, S2, wcomb, bias, dw1, dw2);
    k_pw<<<dim3(1024, 2), 256, 0, stream>>>(dw1, dw2, wpw, bpw, S1, S2, S3);
    k_norm<<<4096, 256, 0, stream>>>(S1, S2, invQ, invK);
    k_qkt<<<512, 512, 0, stream>>>(S1, S2, Sp);
    k_smx<<<1024, 256, 0, stream>>>(Sp, invQ, invK, P);
    k_pv<<<512, 512, 0, stream>>>(P, S3, S1, invQ, S2);
    k_final<<<1024, 256, 0, stream>>>(S2, S12b, wpw, bpw, (float*)d_out);
}